// Round 3
// baseline (9523.305 us; speedup 1.0000x reference)
//
#include <hip/hip_runtime.h>

typedef unsigned int u32;
typedef unsigned short u16;
typedef unsigned long long u64;

// ---------------- problem constants ----------------
// B=2048, CIN=256, NH=512, NF=112, K=112, NL=50, MC=100, NOUT=200
// out (f32 elements): c_prob [2048,112,100] | y [2048,200] | c_hard [2048,112,100]
#define YOFF  22937600ull
#define CHOFF 23347200ull

// workspace offsets (bytes)
#define OFF_HA    0ull          // 2048*512 f32 = 4,194,304 B ; reused as Wp (2.81 MB) after last hA read
#define OFF_HB    4194304ull    // 2048*512 f32               ; reused as mask buffer (3.28 MB) after last hB read
#define OFF_INTER 8388608ull    // 2048*112 f32 = 917,504 B

// ---------------- threefry2x32 (JAX-compatible, partitionable stream) ----------------
__host__ __device__ inline u32 rotl32_(u32 x, int r) { return (x << r) | (x >> (32 - r)); }
__host__ __device__ inline void tf2x32(u32 k0, u32 k1, u32 c0, u32 c1, u32& o0, u32& o1) {
  u32 ks0 = k0, ks1 = k1, ks2 = k0 ^ k1 ^ 0x1BD11BDAu;
  u32 x0 = c0 + ks0, x1 = c1 + ks1;
  const int RA[4] = {13, 15, 26, 6}, RB[4] = {17, 29, 16, 24};
  for (int i = 0; i < 5; ++i) {
    const int* R = (i & 1) ? RB : RA;
    for (int j = 0; j < 4; ++j) { x0 += x1; x1 = rotl32_(x1, R[j]); x1 ^= x0; }
    switch (i) {
      case 0: x0 += ks1; x1 += ks2 + 1u; break;
      case 1: x0 += ks2; x1 += ks0 + 2u; break;
      case 2: x0 += ks0; x1 += ks1 + 3u; break;
      case 3: x0 += ks1; x1 += ks2 + 4u; break;
      case 4: x0 += ks2; x1 += ks0 + 5u; break;
    }
  }
  o0 = x0; o1 = x1;
}

struct SKeys { u32 v[224]; };  // per-step subkeys: sk_i = tf(key_i,(0,1)); key_{i+1} = tf(key_i,(0,0))

// ---------------- generic f32 GEMM: C = act(A@B + bias) ----------------
// 64x64 tile, BK=32, 256 threads, 4x4 per thread.
template <bool DO_LRELU>
__global__ __launch_bounds__(256) void gemm_bias(const float* __restrict__ A,
                                                 const float* __restrict__ Bm,
                                                 const float* __restrict__ bias,
                                                 float* __restrict__ C,
                                                 int M, int N, int K) {
  __shared__ float As[32][65];  // [k][m]
  __shared__ float Bs[32][65];  // [k][n]
  const int bm = blockIdx.y * 64, bn = blockIdx.x * 64;
  const int t = threadIdx.x;
  const int ty = t >> 4, tx = t & 15;
  float acc[4][4] = {};
  for (int k0 = 0; k0 < K; k0 += 32) {
#pragma unroll
    for (int l = 0; l < 2; ++l) {
      int e = l * 256 + t;                // < 512
      int m = e >> 3, k4 = e & 7;         // 64 rows x 8 float4
      float4 v = *(const float4*)(A + (size_t)(bm + m) * K + (k0 + k4 * 4));
      As[k4 * 4 + 0][m] = v.x; As[k4 * 4 + 1][m] = v.y;
      As[k4 * 4 + 2][m] = v.z; As[k4 * 4 + 3][m] = v.w;
    }
#pragma unroll
    for (int l = 0; l < 2; ++l) {
      int e = l * 256 + t;
      int k = e >> 4, n4 = e & 15;        // 32 k x 16 float4
      int gn = bn + n4 * 4;
      if (gn < N) {
        float4 v = *(const float4*)(Bm + (size_t)(k0 + k) * N + gn);
        Bs[k][n4 * 4 + 0] = v.x; Bs[k][n4 * 4 + 1] = v.y;
        Bs[k][n4 * 4 + 2] = v.z; Bs[k][n4 * 4 + 3] = v.w;
      } else {
        Bs[k][n4 * 4 + 0] = 0.f; Bs[k][n4 * 4 + 1] = 0.f;
        Bs[k][n4 * 4 + 2] = 0.f; Bs[k][n4 * 4 + 3] = 0.f;
      }
    }
    __syncthreads();
#pragma unroll
    for (int kk = 0; kk < 32; ++kk) {
      float a[4], b[4];
#pragma unroll
      for (int j = 0; j < 4; ++j) { a[j] = As[kk][ty * 4 + j]; b[j] = Bs[kk][tx * 4 + j]; }
#pragma unroll
      for (int i = 0; i < 4; ++i)
#pragma unroll
        for (int j = 0; j < 4; ++j) acc[i][j] = fmaf(a[i], b[j], acc[i][j]);
    }
    __syncthreads();
  }
#pragma unroll
  for (int i = 0; i < 4; ++i) {
#pragma unroll
    for (int j = 0; j < 4; ++j) {
      int m = bm + ty * 4 + i, n = bn + tx * 4 + j;
      if (n < N) {
        float s = acc[i][j] + bias[n];
        if (DO_LRELU) { if (s < 0.f) s = 0.01f * s; }
        C[(size_t)m * N + n] = s;
      }
    }
  }
}

// ---------------- repack W1 feedback block into 16B-aligned [i][r][sub][28] (zero-padded) ----------------
// Wp[((i*112 + r)*2 + sub)*28 + h] = W1[i][112+r][sub*25+h] for h<25, else 0. Total 2.81 MB -> hA.
__global__ __launch_bounds__(256) void repack_w1(const float* __restrict__ W1, float* __restrict__ Wp) {
  const int i = blockIdx.x;   // 112
  for (int e = threadIdx.x; e < 112 * 56; e += 256) {
    int r = e / 56, c = e - r * 56;
    int sub = c / 28, h = c - sub * 28;
    float v = (h < 25) ? W1[(size_t)i * 11200 + 5600 + r * 50 + sub * 25 + h] : 0.f;
    Wp[(size_t)i * 6272 + e] = v;
  }
}

// ---------------- base_i[b][h] = inter @ W1_i[:112,:] + b1_i  -> staged SUB-PADDED into out c_hard region ----
// Stored at col = (h<25 ? h : h+3) so each lane's 25-float half starts 16B-aligned (cols 0..24 / 28..52).
// c_hard region is only rewritten by expand_kernel afterwards.
__global__ __launch_bounds__(256) void base_kernel(const float* __restrict__ inter,
                                                   const float* __restrict__ W1,
                                                   const float* __restrict__ pb1,
                                                   float* __restrict__ out) {
  __shared__ float As[112][65];  // [k][b]
  __shared__ float Ws[112][64];  // [k][h], zero-padded h>=50
  const int i = blockIdx.y;
  const int b0 = blockIdx.x * 64;
  const int t = threadIdx.x;
  const int ty = t >> 4, tx = t & 15;
#pragma unroll
  for (int l = 0; l < 7; ++l) {
    int e4 = l * 256 + t;               // < 1792 = 64 rows * 28 float4
    int k4 = e4 % 28, bs = e4 / 28;
    float4 v = *(const float4*)(inter + (size_t)(b0 + bs) * 112 + k4 * 4);
    As[k4 * 4 + 0][bs] = v.x; As[k4 * 4 + 1][bs] = v.y;
    As[k4 * 4 + 2][bs] = v.z; As[k4 * 4 + 3][bs] = v.w;
  }
#pragma unroll
  for (int l = 0; l < 28; ++l) {
    int e = l * 256 + t;                // < 7168 = 112*64
    int r = e >> 6, c = e & 63;
    Ws[r][c] = (c < 50) ? W1[(size_t)i * 11200 + r * 50 + c] : 0.f;
  }
  __syncthreads();
  float acc[4][4] = {};
  for (int kk = 0; kk < 112; ++kk) {
    float a[4], b[4];
#pragma unroll
    for (int j = 0; j < 4; ++j) { a[j] = As[kk][ty * 4 + j]; b[j] = Ws[kk][tx * 4 + j]; }
#pragma unroll
    for (int ii = 0; ii < 4; ++ii)
#pragma unroll
      for (int j = 0; j < 4; ++j) acc[ii][j] = fmaf(a[ii], b[j], acc[ii][j]);
  }
#pragma unroll
  for (int ii = 0; ii < 4; ++ii) {
#pragma unroll
    for (int j = 0; j < 4; ++j) {
      int b = b0 + ty * 4 + ii, h = tx * 4 + j;
      if (h < 50) {
        int col = (h < 25) ? h : h + 3;
        out[CHOFF + (size_t)b * 11200 + (size_t)i * 100 + col] = acc[ii][j] + pb1[i * 50 + h];
      }
    }
  }
}

// ---------------- sequential concept sampling: LANE-PAIR SPLIT (h-halves on lanes 2j / 2j+1) -----------------
// 1600 blocks x 256 threads; pair = blockIdx*128 + t>>1, sub = t&1 owns h in [sub*25, sub*25+25).
// 6400 waves (78% grid occupancy) vs round-0's 3280; per-thread state halves (acc[25]).
// No barriers, no LDS: the only cross-thread exchange is __shfl_xor(.,1) between the two lanes
// of a pair (lockstep within a wave). Both lanes then execute the IDENTICAL ordered 50-term
// fmaf dot (cndmask-selected own/received values -> bit-exact), so both compute identical
// s/pr/u/sample-bit and keep private copies of the history masks — sampling cannot flip:
// per-h r-chains keep exact order, fmaf(c,w,acc) with c in {0,1} is exact, and the dot chain
// consumes bitwise-equal v values in the exact reference order.
// Weight rows come from the repacked 16B-aligned Wp (vector float4 loads, 2 distinct
// addresses per wave per load -> 1-2 L1 lines); base rows from the sub-padded staging.
// Masks go to the dead hB workspace (expand_kernel materializes c_hard afterwards).
__global__ __launch_bounds__(256, 5) void sample_kernel4(const float* __restrict__ Wp,
                                                         const float* __restrict__ W2,
                                                         const float* __restrict__ b2v,
                                                         float* __restrict__ out,
                                                         u32* __restrict__ masks, SKeys sks) {
  const int t = threadIdx.x;
  const int sub = t & 1;
  const int p = blockIdx.x * 128 + (t >> 1);   // pair id = b*100 + m, exact cover (1600*128 = 204800)
  const int b = p / 100;
  const int m = p - b * 100;
  const float* __restrict__ baseb = out + CHOFF + (size_t)b * 11200 + sub * 28;  // 16B-aligned
  const float* __restrict__ Wsub = Wp + sub * 28;                                 // 16B-aligned
  u64 lo = 0, hi = 0;
  float acc[25], rcv[25];

  for (int i = 0; i < 112; ++i) {
#pragma unroll
    for (int h = 0; h < 25; ++h) acc[h] = 0.f;
    // ---- feedback r-loop: acc[h] += c_r * W[r][h-half], exact r order ----
    {
      const float* __restrict__ Wi = Wsub + (size_t)i * 6272;
      int r = 0;
      int r1 = (i < 64) ? i : 64;
      u64 cm = lo;
      for (; r < r1; ++r) {
        float c = (cm & 1ull) ? 1.f : 0.f;
        cm >>= 1;
        const float* __restrict__ wr = Wi + r * 56;
        float4 q0 = ((const float4*)wr)[0];
        float4 q1 = ((const float4*)wr)[1];
        float4 q2 = ((const float4*)wr)[2];
        float4 q3 = ((const float4*)wr)[3];
        float4 q4 = ((const float4*)wr)[4];
        float4 q5 = ((const float4*)wr)[5];
        float w24 = wr[24];
        acc[0] = fmaf(c, q0.x, acc[0]);  acc[1] = fmaf(c, q0.y, acc[1]);
        acc[2] = fmaf(c, q0.z, acc[2]);  acc[3] = fmaf(c, q0.w, acc[3]);
        acc[4] = fmaf(c, q1.x, acc[4]);  acc[5] = fmaf(c, q1.y, acc[5]);
        acc[6] = fmaf(c, q1.z, acc[6]);  acc[7] = fmaf(c, q1.w, acc[7]);
        acc[8] = fmaf(c, q2.x, acc[8]);  acc[9] = fmaf(c, q2.y, acc[9]);
        acc[10] = fmaf(c, q2.z, acc[10]); acc[11] = fmaf(c, q2.w, acc[11]);
        acc[12] = fmaf(c, q3.x, acc[12]); acc[13] = fmaf(c, q3.y, acc[13]);
        acc[14] = fmaf(c, q3.z, acc[14]); acc[15] = fmaf(c, q3.w, acc[15]);
        acc[16] = fmaf(c, q4.x, acc[16]); acc[17] = fmaf(c, q4.y, acc[17]);
        acc[18] = fmaf(c, q4.z, acc[18]); acc[19] = fmaf(c, q4.w, acc[19]);
        acc[20] = fmaf(c, q5.x, acc[20]); acc[21] = fmaf(c, q5.y, acc[21]);
        acc[22] = fmaf(c, q5.z, acc[22]); acc[23] = fmaf(c, q5.w, acc[23]);
        acc[24] = fmaf(c, w24, acc[24]);
      }
      cm = hi;
      for (; r < i; ++r) {
        float c = (cm & 1ull) ? 1.f : 0.f;
        cm >>= 1;
        const float* __restrict__ wr = Wi + r * 56;
        float4 q0 = ((const float4*)wr)[0];
        float4 q1 = ((const float4*)wr)[1];
        float4 q2 = ((const float4*)wr)[2];
        float4 q3 = ((const float4*)wr)[3];
        float4 q4 = ((const float4*)wr)[4];
        float4 q5 = ((const float4*)wr)[5];
        float w24 = wr[24];
        acc[0] = fmaf(c, q0.x, acc[0]);  acc[1] = fmaf(c, q0.y, acc[1]);
        acc[2] = fmaf(c, q0.z, acc[2]);  acc[3] = fmaf(c, q0.w, acc[3]);
        acc[4] = fmaf(c, q1.x, acc[4]);  acc[5] = fmaf(c, q1.y, acc[5]);
        acc[6] = fmaf(c, q1.z, acc[6]);  acc[7] = fmaf(c, q1.w, acc[7]);
        acc[8] = fmaf(c, q2.x, acc[8]);  acc[9] = fmaf(c, q2.y, acc[9]);
        acc[10] = fmaf(c, q2.z, acc[10]); acc[11] = fmaf(c, q2.w, acc[11]);
        acc[12] = fmaf(c, q3.x, acc[12]); acc[13] = fmaf(c, q3.y, acc[13]);
        acc[14] = fmaf(c, q3.z, acc[14]); acc[15] = fmaf(c, q3.w, acc[15]);
        acc[16] = fmaf(c, q4.x, acc[16]); acc[17] = fmaf(c, q4.y, acc[17]);
        acc[18] = fmaf(c, q4.z, acc[18]); acc[19] = fmaf(c, q4.w, acc[19]);
        acc[20] = fmaf(c, q5.x, acc[20]); acc[21] = fmaf(c, q5.y, acc[21]);
        acc[22] = fmaf(c, q5.z, acc[22]); acc[23] = fmaf(c, q5.w, acc[23]);
        acc[24] = fmaf(c, w24, acc[24]);
      }
    }
    // ---- own half: v = lrelu(acc + base), in place (float4 base loads, aligned by construction) ----
    {
      const float* __restrict__ bs = baseb + (size_t)i * 100;
#pragma unroll
      for (int j = 0; j < 6; ++j) {
        float4 q = ((const float4*)bs)[j];
        float x;
        x = acc[4 * j + 0] + q.x; acc[4 * j + 0] = (x < 0.f) ? 0.01f * x : x;
        x = acc[4 * j + 1] + q.y; acc[4 * j + 1] = (x < 0.f) ? 0.01f * x : x;
        x = acc[4 * j + 2] + q.z; acc[4 * j + 2] = (x < 0.f) ? 0.01f * x : x;
        x = acc[4 * j + 3] + q.w; acc[4 * j + 3] = (x < 0.f) ? 0.01f * x : x;
      }
      float x = acc[24] + bs[24]; acc[24] = (x < 0.f) ? 0.01f * x : x;
    }
    // ---- exchange halves with partner lane (lane^1), no barriers ----
#pragma unroll
    for (int h = 0; h < 25; ++h) rcv[h] = __shfl_xor(acc[h], 1, 64);
    // ---- ordered 50-term dot, identical on both lanes (bit-exact cndmask selects) ----
    const float* __restrict__ w2 = W2 + i * 50;   // wave-uniform -> s_load
    float s = 0.f;
#pragma unroll
    for (int h = 0; h < 25; ++h) { float val = sub ? rcv[h] : acc[h]; s = fmaf(val, w2[h], s); }
#pragma unroll
    for (int h = 0; h < 25; ++h) { float val = sub ? acc[h] : rcv[h]; s = fmaf(val, w2[25 + h], s); }
    float l = s + b2v[i];
    float pr = 1.f / (1.f + expf(-l));
    // JAX f32 uniform: bits = o0^o1 of tf(sk_i,(0,p)); u = bitcast((bits>>9)|0x3F800000)-1
    u32 a0, a1;
    tf2x32(sks.v[2 * i], sks.v[2 * i + 1], 0u, (u32)p, a0, a1);
    u32 fb = ((a0 ^ a1) >> 9) | 0x3F800000u;
    float uu; __builtin_memcpy(&uu, &fb, 4); uu -= 1.f;
    u64 sbit = (uu < pr) ? 1ull : 0ull;
    if (!sub) out[(size_t)b * 11200 + (size_t)i * 100 + m] = pr;   // c_prob (owned cell)
    if (i < 64) lo |= sbit << i; else hi |= sbit << (i - 64);
  }
  // ---- store history masks (even lane of each pair), coalesced, into dead hB workspace ----
  if (!sub) {
    u32* mp = masks + (size_t)p * 4;
    mp[0] = (u32)lo; mp[1] = (u32)(lo >> 32);
    mp[2] = (u32)hi; mp[3] = (u32)(hi >> 32);
  }
}

// ---------------- expand masks -> c_hard (memory-bound) ----------------
// one block per batch b; reads packed masks from workspace, writes all 11200 cells
__global__ __launch_bounds__(256) void expand_kernel(const u32* __restrict__ masks,
                                                     float* __restrict__ out) {
  __shared__ u32 mW[100][4];
  const int b = blockIdx.x;
  const int t = threadIdx.x;
  if (t < 100) {
    const u32* mp = masks + ((size_t)b * 100 + t) * 4;
    mW[t][0] = mp[0]; mW[t][1] = mp[1]; mW[t][2] = mp[2]; mW[t][3] = mp[3];
  }
  __syncthreads();
  for (int e = t; e < 11200; e += 256) {
    int i = e / 100, m = e - i * 100;
    u32 word = mW[m][i >> 5];
    out[CHOFF + (size_t)b * 11200 + e] = (float)((word >> (i & 31)) & 1u);
  }
}

// ---------------- head: logits -> softmax -> mean over m -> log ----------------
// one block per b; 256 threads
__global__ __launch_bounds__(256) void head_kernel(const float* __restrict__ HW,
                                                   const float* __restrict__ hb,
                                                   float* __restrict__ out) {
  __shared__ unsigned char cS[100][116];
  __shared__ float lgS[50][201];
  const int b = blockIdx.x;
  const int t = threadIdx.x;
  for (int e = t; e < 11200; e += 256) {
    int k = e / 100, m = e - k * 100;
    cS[m][k] = (out[CHOFF + (size_t)b * 11200 + (size_t)k * 100 + m] != 0.f) ? 1 : 0;
  }
  __syncthreads();
  float pacc = 0.f;
  for (int mh = 0; mh < 2; ++mh) {
    for (int l = 0; l < 3; ++l) {
      int tile = l * 256 + t;
      if (tile < 625) {                    // 25 o-chunks x 25 m-chunks
        int o0 = (tile % 25) * 8;
        int m0 = (tile / 25) * 2;
        float acc[2][8] = {};
        for (int k = 0; k < 112; ++k) {
          float4 wa = *(const float4*)(HW + (size_t)k * 200 + o0);
          float4 wb = *(const float4*)(HW + (size_t)k * 200 + o0 + 4);
          float w[8] = {wa.x, wa.y, wa.z, wa.w, wb.x, wb.y, wb.z, wb.w};
          float c0 = (float)cS[mh * 50 + m0][k];
          float c1 = (float)cS[mh * 50 + m0 + 1][k];
#pragma unroll
          for (int jo = 0; jo < 8; ++jo) {
            acc[0][jo] = fmaf(c0, w[jo], acc[0][jo]);
            acc[1][jo] = fmaf(c1, w[jo], acc[1][jo]);
          }
        }
#pragma unroll
        for (int im = 0; im < 2; ++im)
#pragma unroll
          for (int jo = 0; jo < 8; ++jo) {
            int o = o0 + jo;
            lgS[m0 + im][o] = acc[im][jo] + hb[o];
          }
      }
    }
    __syncthreads();
    if (t < 50) {
      int m = t;
      float mx = -3.0e38f;
      for (int o = 0; o < 200; ++o) mx = fmaxf(mx, lgS[m][o]);
      float s = 0.f;
      for (int o = 0; o < 200; ++o) {
        float e = expf(lgS[m][o] - mx);
        lgS[m][o] = e; s += e;
      }
      float inv = 1.f / s;
      for (int o = 0; o < 200; ++o) lgS[m][o] = lgS[m][o] * inv;
    }
    __syncthreads();
    if (t < 200) { for (int m = 0; m < 50; ++m) pacc += lgS[m][t]; }
    __syncthreads();
  }
  if (t < 200) {
    out[YOFF + (size_t)b * 200 + t] = logf(pacc / 100.f + 1e-6f);
  }
}

// ---------------- launcher ----------------
extern "C" void kernel_launch(void* const* d_in, const int* in_sizes, int n_in,
                              void* d_out, int out_size, void* d_ws, size_t ws_size,
                              hipStream_t stream) {
  const float* x    = (const float*)d_in[0];
  const float* Win  = (const float*)d_in[1];
  const float* bin  = (const float*)d_in[2];
  const float* Wh   = (const float*)d_in[3];
  const float* bh   = (const float*)d_in[4];
  const float* Wout = (const float*)d_in[5];
  const float* bout = (const float*)d_in[6];
  const float* pW1  = (const float*)d_in[7];
  const float* pb1  = (const float*)d_in[8];
  const float* pW2  = (const float*)d_in[9];
  const float* pb2  = (const float*)d_in[10];
  const float* hW   = (const float*)d_in[11];
  const float* hb   = (const float*)d_in[12];
  float* out = (float*)d_out;
  char* ws = (char*)d_ws;

  float* hA     = (float*)(ws + OFF_HA);
  float* hB     = (float*)(ws + OFF_HB);
  float* interB = (float*)(ws + OFF_INTER);
  float* Wp     = (float*)(ws + OFF_HA);   // alias: dead after inter-gemm
  u32*   masks  = (u32*)(ws + OFF_HB);     // alias: dead after last hB-reading gemm

  gemm_bias<true ><<<dim3(8, 32), 256, 0, stream>>>(x,  Win,             bin,          hA,     2048, 512, 256);
  gemm_bias<true ><<<dim3(8, 32), 256, 0, stream>>>(hA, Wh + 0 * 262144, bh + 0 * 512, hB,     2048, 512, 512);
  gemm_bias<true ><<<dim3(8, 32), 256, 0, stream>>>(hB, Wh + 1 * 262144, bh + 1 * 512, hA,     2048, 512, 512);
  gemm_bias<true ><<<dim3(8, 32), 256, 0, stream>>>(hA, Wh + 2 * 262144, bh + 2 * 512, hB,     2048, 512, 512);
  gemm_bias<true ><<<dim3(8, 32), 256, 0, stream>>>(hB, Wh + 3 * 262144, bh + 3 * 512, hA,     2048, 512, 512);
  gemm_bias<false><<<dim3(2, 32), 256, 0, stream>>>(hA, Wout,            bout,         interB, 2048, 112, 512);

  // hA is dead from here on -> repack W1 feedback block into it (16B-aligned [i][r][sub][28])
  repack_w1<<<112, 256, 0, stream>>>(pW1, Wp);

  base_kernel<<<dim3(32, 112), 256, 0, stream>>>(interB, pW1, pb1, out);

  // host-side key chain: key(42)=(0,42); partitionable split: key'=tf(key,(0,0)), sk=tf(key,(0,1))
  SKeys sks;
  {
    u32 k0 = 0u, k1 = 42u;
    for (int i = 0; i < 112; ++i) {
      u32 nk0, nk1, s0, s1;
      tf2x32(k0, k1, 0u, 0u, nk0, nk1);
      tf2x32(k0, k1, 0u, 1u, s0, s1);
      sks.v[2 * i] = s0; sks.v[2 * i + 1] = s1;
      k0 = nk0; k1 = nk1;
    }
  }
  sample_kernel4<<<1600, 256, 0, stream>>>(Wp, pW2, pb2, out, masks, sks);
  expand_kernel<<<2048, 256, 0, stream>>>(masks, out);

  head_kernel<<<2048, 256, 0, stream>>>(hW, hb, out);
}